// Round 15
// baseline (634.912 us; speedup 1.0000x reference)
//
#include <hip/hip_runtime.h>
#include <hip/hip_fp16.h>
#include <math.h>

// ---------------------------------------------------------------------------
// Sender model, MI355X, round 15 = R14 + logits A-operand in registers.
// All GEMMs on fp16x2 (Markidis) MFMA: 3 products, fp32 accumulate.
// logits: A (h0/h1) fragments loaded DIRECTLY global->VGPR (16 lines/instr,
// one 64B line per row per K-step); only B (w0/w1) staged in LDS (16 KB).
// Halves LDS port traffic (16->8 ds_read_b128 per wave-step) and staging
// instructions; A-load latency drains under the existing vmcnt(0)+barrier.
// embgk table (R14), gru/finalize fusions, fast-math micro-opts retained.
// ---------------------------------------------------------------------------

typedef __attribute__((ext_vector_type(8))) _Float16 half8v;  // 16 B
typedef __attribute__((ext_vector_type(4))) float f32x4;

// slot swizzle; row stride 64 B
__device__ __forceinline__ int lds_off(int row, int slot) {
    return (row << 6) + ((slot ^ (row & 3) ^ ((row >> 2) & 3)) << 4);
}

__device__ __forceinline__ void gld_lds16(const void* src, void* dst) {
    __builtin_amdgcn_global_load_lds(
        (const __attribute__((address_space(1))) void*)src,
        (__attribute__((address_space(3))) void*)dst, 16, 0, 0);
}

template<int C>
__device__ __forceinline__ float dppf(float x) {
    return __builtin_bit_cast(float, __builtin_amdgcn_update_dpp(
        __builtin_bit_cast(int, x), __builtin_bit_cast(int, x), C, 0xF, 0xF, false));
}
template<int C>
__device__ __forceinline__ int dppi(int x) {
    return __builtin_amdgcn_update_dpp(x, x, C, 0xF, 0xF, false);
}

__device__ __forceinline__ void f16split(float v, unsigned short& u0,
                                         unsigned short& u1) {
    __half a = __float2half(v);            // RTNE
    float f = __half2float(a);
    __half b = __float2half(v - f);
    u0 = __half_as_ushort(a);
    u1 = __half_as_ushort(b);
}

__device__ __forceinline__ float fast_tanh(float x) {
    float t = __expf(-2.0f * fabsf(x));    // t in (0,1], no overflow
    float th = (1.0f - t) / (1.0f + t);
    return copysignf(th, x);
}

// ---------------- elementwise fp16x2 split (vis, emb) -----------------------
__global__ __launch_bounds__(256) void split_ew(
    const float* __restrict__ in, unsigned short* __restrict__ o0,
    unsigned short* __restrict__ o1, int n4)
{
    int i = blockIdx.x * 256 + threadIdx.x;
    if (i >= n4) return;
    float4 v = *(const float4*)&in[(size_t)i * 4];
    unsigned short a[4], b[4];
    f16split(v.x, a[0], b[0]); f16split(v.y, a[1], b[1]);
    f16split(v.z, a[2], b[2]); f16split(v.w, a[3], b[3]);
    *(uint2*)&o0[(size_t)i * 4] = *(uint2*)a;
    *(uint2*)&o1[(size_t)i * 4] = *(uint2*)b;
}

// ---------------- W[K][N] -> [n][k] fp16x2 splits (Wo, Wv, grk, gk) ---------
__global__ __launch_bounds__(256) void trans_split(
    const float* __restrict__ W, unsigned short* __restrict__ o0,
    unsigned short* __restrict__ o1, int N, int K)
{
    __shared__ float Ts[64][65];
    const int tid = threadIdx.x;
    const int n0 = blockIdx.x * 64, k0 = blockIdx.y * 64;
    const int ty = tid >> 2, tx = tid & 3;
    #pragma unroll
    for (int q = 0; q < 4; ++q) {
        float4 v = *(const float4*)&W[(size_t)(k0 + ty) * N + n0 + tx * 16 + q * 4];
        Ts[ty][tx * 16 + q * 4 + 0] = v.x; Ts[ty][tx * 16 + q * 4 + 1] = v.y;
        Ts[ty][tx * 16 + q * 4 + 2] = v.z; Ts[ty][tx * 16 + q * 4 + 3] = v.w;
    }
    __syncthreads();
    #pragma unroll
    for (int ii = 0; ii < 2; ++ii) {
        int item = tid + (ii << 8);          // 0..511
        int n = item >> 3, g = item & 7;     // n 0..63, k-group 0..7
        unsigned short u0[8], u1[8];
        #pragma unroll
        for (int e = 0; e < 8; ++e)
            f16split(Ts[g * 8 + e][n], u0[e], u1[e]);
        size_t base = (size_t)(n0 + n) * K + k0 + g * 8;
        *(uint4*)&o0[base] = *(uint4*)u0;
        *(uint4*)&o1[base] = *(uint4*)u1;
    }
}

// ---------------- fp16x2 MFMA GEMM, 64x64 tile (K1, K2, embgk) --------------
template<int KTOT, bool SPLIT>
__global__ __launch_bounds__(256) void mfma_gemm(
    const unsigned short* __restrict__ a0s, const unsigned short* __restrict__ a1s,
    const unsigned short* __restrict__ b0s, const unsigned short* __restrict__ b1s,
    const float* __restrict__ bias, float* __restrict__ C, int ldc,
    unsigned short* __restrict__ s0, unsigned short* __restrict__ s1)
{
    __shared__ char lds[16384];
    const int tid = threadIdx.x;
    const int w = tid >> 6, lane = tid & 63;
    const int c16 = lane & 15, rg = lane >> 4;
    const int m0 = blockIdx.y << 6, n0 = blockIdx.x << 6;
    const int arow0 = (w >> 1) << 5, brow0 = (w & 1) << 5;

    const unsigned short* segsrc = (w == 0) ? a0s : (w == 1) ? a1s
                                 : (w == 2) ? b0s : b1s;
    const int segrow0 = (w < 2) ? m0 : n0;

    f32x4 acc[2][2] = {};

    for (int t = 0; t < KTOT / 32; ++t) {
        const int k0 = t << 5;
        #pragma unroll
        for (int q = 0; q < 4; ++q) {
            int row = (q << 4) + (lane >> 2);
            int slot = (lane & 3) ^ (row & 3) ^ ((row >> 2) & 3);
            gld_lds16(segsrc + (size_t)(segrow0 + row) * KTOT + k0 + (slot << 3),
                      &lds[(w << 12) + (q << 10)]);
        }
        asm volatile("s_waitcnt vmcnt(0)" ::: "memory");
        __syncthreads();
        half8v afr[2][2], bfr[2][2];
        #pragma unroll
        for (int i = 0; i < 2; ++i) {
            int oa = lds_off(arow0 + (i << 4) + c16, rg);
            afr[i][0] = *(half8v*)&lds[oa];
            afr[i][1] = *(half8v*)&lds[4096 + oa];
            int ob = lds_off(brow0 + (i << 4) + c16, rg);
            bfr[i][0] = *(half8v*)&lds[8192 + ob];
            bfr[i][1] = *(half8v*)&lds[12288 + ob];
        }
        #pragma unroll
        for (int i = 0; i < 2; ++i)
            #pragma unroll
            for (int j = 0; j < 2; ++j) {
                f32x4 c = acc[i][j];
                c = __builtin_amdgcn_mfma_f32_16x16x32_f16(afr[i][0], bfr[j][0], c, 0, 0, 0);
                c = __builtin_amdgcn_mfma_f32_16x16x32_f16(afr[i][1], bfr[j][0], c, 0, 0, 0);
                c = __builtin_amdgcn_mfma_f32_16x16x32_f16(afr[i][0], bfr[j][1], c, 0, 0, 0);
                acc[i][j] = c;
            }
        __syncthreads();
    }

    #pragma unroll
    for (int j = 0; j < 2; ++j) {
        int col = n0 + brow0 + (j << 4) + c16;
        float bb = bias ? bias[col] : 0.0f;
        #pragma unroll
        for (int i = 0; i < 2; ++i)
            #pragma unroll
            for (int reg = 0; reg < 4; ++reg) {
                int row = m0 + arow0 + (i << 4) + (rg << 2) + reg;
                float v = acc[i][j][reg] + bb;
                C[(size_t)row * ldc + col] = v;
                if (SPLIT) {
                    unsigned short u0, u1;
                    f16split(v, u0, u1);
                    s0[(size_t)row * ldc + col] = u0;
                    s1[(size_t)row * ldc + col] = u1;
                }
            }
    }
}

// ---------------- gru_fused: merge(t-1) + embgk gather + GRU + h split ------
__global__ __launch_bounds__(256) void gru_fused(
    const float4* __restrict__ pstats, const float* __restrict__ emb,
    const float* __restrict__ embgk,
    const float* __restrict__ gk, const float* __restrict__ b_in,
    const float* __restrict__ hm, const float* __restrict__ ph,
    unsigned short* __restrict__ h0, unsigned short* __restrict__ h1,
    float* __restrict__ ht_out, float* __restrict__ out_seq,
    float* __restrict__ out_sel, float* __restrict__ out_ent, int t)
{
    __shared__ float xsT[64][8];
    __shared__ int syms_lds[8];
    const int tid = threadIdx.x;
    const int row0 = blockIdx.x * 8;
    float az[8], ar[8], ah[8];
    const float bz = b_in[tid], br = b_in[256 + tid], bh = b_in[512 + tid];
    #pragma unroll
    for (int r = 0; r < 8; ++r) { az[r] = bz; ar[r] = br; ah[r] = bh; }

    if (t > 0) {
        const int r = tid >> 5, p = tid & 31;
        const int row = row0 + r;
        float4 pa = pstats[(size_t)p * 8192 + row];
        float4 pb = pstats[(size_t)(p + 32) * 8192 + row];
        float M = pa.x, S = pa.y + pb.y, Q = pa.z + pb.z;
        int A = __float_as_int(pa.w);
        { int a2 = __float_as_int(pb.w);
          if (pb.x > M || (pb.x == M && a2 < A)) { M = pb.x; A = a2; } }
        #pragma unroll
        for (int off = 1; off < 32; off <<= 1) {
            float m2 = __shfl_xor(M, off);
            float s2 = __shfl_xor(S, off);
            float q2 = __shfl_xor(Q, off);
            int   a2 = __shfl_xor(A, off);
            S += s2; Q += q2;
            if (m2 > M || (m2 == M && a2 < A)) { M = m2; A = a2; }
        }
        if (p == 0) {
            float lse = __logf(S);
            float sel = M - lse;
            float ent = lse - Q / S;
            out_seq[(size_t)row * 6 + (t - 1)] = (float)A;
            out_sel[(size_t)row * 6 + (t - 1)] = sel;
            float ea = (t == 1) ? ent : (out_ent[row] + ent);
            out_ent[row] = ea;
            syms_lds[r] = A;
        }
        __syncthreads();
        if (embgk) {
            #pragma unroll
            for (int r2 = 0; r2 < 8; ++r2) {
                size_t b = (size_t)syms_lds[r2] * 768 + tid;
                az[r2] += embgk[b];
                ar[r2] += embgk[b + 256];
                ah[r2] += embgk[b + 512];
            }
        } else {
            for (int l = tid; l < 512; l += 256) {
                int r2 = l >> 6, e = l & 63;
                xsT[e][r2] = emb[(size_t)syms_lds[r2] * 64 + e];
            }
            __syncthreads();
            #pragma unroll 4
            for (int e = 0; e < 64; ++e) {
                float kz  = gk[e * 768 + tid];
                float kr_ = gk[e * 768 + 256 + tid];
                float kh  = gk[e * 768 + 512 + tid];
                float4 x0 = *(float4*)&xsT[e][0];
                float4 x1 = *(float4*)&xsT[e][4];
                float xv[8] = {x0.x, x0.y, x0.z, x0.w, x1.x, x1.y, x1.z, x1.w};
                #pragma unroll
                for (int r2 = 0; r2 < 8; ++r2) {
                    az[r2] = fmaf(xv[r2], kz, az[r2]);
                    ar[r2] = fmaf(xv[r2], kr_, ar[r2]);
                    ah[r2] = fmaf(xv[r2], kh, ah[r2]);
                }
            }
        }
    }
    #pragma unroll
    for (int r = 0; r < 8; ++r) {
        const int row = row0 + r;
        float hz  = hm[(size_t)row * 768 + tid];
        float hr  = hm[(size_t)row * 768 + 256 + tid];
        float hh  = hm[(size_t)row * 768 + 512 + tid];
        float phv = ph[(size_t)row * 256 + tid];
        float z  = 1.0f / (1.0f + __expf(-(az[r] + hz)));
        float rr = 1.0f / (1.0f + __expf(-(ar[r] + hr)));
        float ht = fast_tanh(ah[r] + rr * hh);
        float hv = z * phv + (1.0f - z) * ht;
        size_t idx = (size_t)row * 256 + tid;
        unsigned short u0, u1;
        f16split(hv, u0, u1);
        h0[idx] = u0; h1[idx] = u1;
        if (ht_out) ht_out[idx] = hv;
    }
}

// ---------------- logits: 128x128 fp16x2 MFMA, A in regs, B in 16 KB LDS ----
// 4 waves (2x2), wave tile 64x64 = 4x4 frags of 16x16x32 f16, 3 products.
// A-frags: per-lane 16B direct global loads (16 cache lines/instr; one 64B
// line per row per K-step). B: 16 gld_lds split 4/wave into one 16 KB buffer.
// Same vmcnt(0)+barrier drain covers both. LDS reads: 8/wave-step (was 16).
__global__ __launch_bounds__(256, 3) void logits_mfma(
    const unsigned short* __restrict__ h0, const unsigned short* __restrict__ h1,
    const unsigned short* __restrict__ w0, const unsigned short* __restrict__ w1,
    const float* __restrict__ bo, float4* __restrict__ pstats)
{
    __shared__ char lds[16384];            // B: w0 seg 8 KB | w1 seg 8 KB
    const int tid = threadIdx.x;
    const int w = tid >> 6, lane = tid & 63;
    const int c16 = lane & 15, rg = lane >> 4;
    const int m0 = blockIdx.y << 7, n0 = blockIdx.x << 7;
    const int arow0 = (w >> 1) << 6, brow0 = (w & 1) << 6;

    // per-lane A fragment base offsets (shorts); K-step adds t*32
    size_t abase[4];
    #pragma unroll
    for (int i = 0; i < 4; ++i)
        abase[i] = (size_t)(m0 + arow0 + (i << 4) + c16) * 256 + rg * 8;

    // B staging: wave w handles units g = 4w..4w+3; seg = g>>3, group = g&7
    const unsigned short* bsrc = (w < 2) ? w0 : w1;
    const int bseg = (w >> 1) << 13;       // 0 or 8192

    f32x4 acc[4][4] = {};

    for (int t = 0; t < 8; ++t) {
        const int k0 = t << 5;
        half8v afr[4][2];
        #pragma unroll
        for (int i = 0; i < 4; ++i) {      // A direct to registers
            afr[i][0] = *(const half8v*)(h0 + abase[i] + k0);
            afr[i][1] = *(const half8v*)(h1 + abase[i] + k0);
        }
        #pragma unroll
        for (int q = 0; q < 4; ++q) {      // B staging (this wave's 4 units)
            int grp = ((w & 1) << 2) + q;  // waves 0,2 -> groups 0-3; 1,3 -> 4-7
            int row = (grp << 4) + (lane >> 2);
            int slot = (lane & 3) ^ (row & 3) ^ ((row >> 2) & 3);
            gld_lds16(bsrc + (size_t)(n0 + row) * 256 + k0 + (slot << 3),
                      &lds[bseg + (grp << 10)]);
        }
        asm volatile("s_waitcnt vmcnt(0)" ::: "memory");
        __syncthreads();
        #pragma unroll
        for (int j = 0; j < 4; ++j) {
            int o = lds_off(brow0 + (j << 4) + c16, rg);
            half8v b0 = *(half8v*)&lds[o];          // w0 segment
            half8v b1 = *(half8v*)&lds[8192 + o];   // w1 segment
            #pragma unroll
            for (int i = 0; i < 4; ++i) {
                f32x4 c = acc[i][j];
                c = __builtin_amdgcn_mfma_f32_16x16x32_f16(afr[i][0], b0, c, 0, 0, 0);
                c = __builtin_amdgcn_mfma_f32_16x16x32_f16(afr[i][1], b0, c, 0, 0, 0);
                c = __builtin_amdgcn_mfma_f32_16x16x32_f16(afr[i][0], b1, c, 0, 0, 0);
                acc[i][j] = c;
            }
        }
        __syncthreads();
    }

    // epilogue: raw softmax stats + DPP reductions across the 16 c16 lanes.
    const int wn0 = n0 + brow0;
    float bov[4];
    #pragma unroll
    for (int j = 0; j < 4; ++j) bov[j] = bo[wn0 + j * 16 + c16];
    #pragma unroll
    for (int i = 0; i < 4; ++i) {
        #pragma unroll
        for (int reg = 0; reg < 4; ++reg) {
            float l0 = acc[i][0][reg] + bov[0];
            float l1 = acc[i][1][reg] + bov[1];
            float l2 = acc[i][2][reg] + bov[2];
            float l3 = acc[i][3][reg] + bov[3];
            float m = l0; int a = wn0 + c16;
            if (l1 > m) { m = l1; a = wn0 + 16 + c16; }
            if (l2 > m) { m = l2; a = wn0 + 32 + c16; }
            if (l3 > m) { m = l3; a = wn0 + 48 + c16; }
            float e0 = __expf(l0), e1 = __expf(l1), e2 = __expf(l2), e3 = __expf(l3);
            float s = (e0 + e1) + (e2 + e3);
            float q = fmaf(l0, e0, fmaf(l1, e1, fmaf(l2, e2, l3 * e3)));
            s += dppf<0x108>(s); s += dppf<0x104>(s);
            s += dppf<0x102>(s); s += dppf<0x101>(s);
            q += dppf<0x108>(q); q += dppf<0x104>(q);
            q += dppf<0x102>(q); q += dppf<0x101>(q);
            #define MMERGE(C) { float m2 = dppf<C>(m); int a2 = dppi<C>(a); \
                bool bt = (m2 > m) || (m2 == m && a2 < a); \
                m = bt ? m2 : m; a = bt ? a2 : a; }
            MMERGE(0x108) MMERGE(0x104) MMERGE(0x102) MMERGE(0x101)
            #undef MMERGE
            if (c16 == 0) {
                int grow = m0 + arow0 + (i << 4) + (rg << 2) + reg;
                pstats[(size_t)((blockIdx.x << 1) + (w & 1)) * 8192 + grow] =
                    make_float4(m, s, q, __int_as_float(a));
            }
        }
    }
}

// ---------------- final finalize: merge t=5 panels, close outputs -----------
__global__ __launch_bounds__(64) void finalize_kernel(
    const float4* __restrict__ pstats, float* __restrict__ out_seq,
    float* __restrict__ out_sel, float* __restrict__ out_ent,
    float* __restrict__ out_ml)
{
    const int row = blockIdx.x * 64 + threadIdx.x;
    float M = -INFINITY, S = 0.f, Q = 0.f; int A = 0;
    #pragma unroll 8
    for (int p = 0; p < 64; ++p) {
        float4 pp = pstats[(size_t)p * 8192 + row];
        S += pp.y; Q += pp.z;
        int a2 = __float_as_int(pp.w);
        if (pp.x > M || (pp.x == M && a2 < A)) { M = pp.x; A = a2; }
    }
    float lse = __logf(S);
    float sel = M - lse;
    float ent = lse - Q / S;
    out_seq[(size_t)row * 6 + 5] = (float)A;
    out_sel[(size_t)row * 6 + 5] = sel;
    out_ent[row] = (out_ent[row] + ent) * (1.0f / 6.0f);
    out_ml[row] = 6.0f;
}

// ---------------------------------------------------------------------------
extern "C" void kernel_launch(void* const* d_in, const int* in_sizes, int n_in,
                              void* d_out, int out_size, void* d_ws, size_t ws_size,
                              hipStream_t stream) {
    const float* vis  = (const float*)d_in[0];
    const float* Wv   = (const float*)d_in[1];
    const float* bv   = (const float*)d_in[2];
    const float* gk   = (const float*)d_in[3];
    const float* grk  = (const float*)d_in[4];
    const float* bin  = (const float*)d_in[5];
    const float* brec = (const float*)d_in[6];
    const float* Wo   = (const float*)d_in[7];
    const float* bo   = (const float*)d_in[8];
    const float* emb  = (const float*)d_in[9];

    float* out = (float*)d_out;
    float* out_seq = out;                 // (8192, 6)
    float* out_sel = out + 49152;         // (8192, 6)
    float* out_ent = out + 98304;         // (8192,)
    float* out_ml  = out + 106496;        // (8192,)
    float* out_ht  = out + 114688;        // (8192, 256)

    char* ws = (char*)d_ws;
    float*          ph     = (float*)(ws);                       // 8 MB
    float*          hm     = (float*)(ws + 8388608);             // 24 MB
    unsigned short* vis0   = (unsigned short*)(ws + 8388608);    // 8 MB (overlay hm; dead before K2)
    unsigned short* vis1   = (unsigned short*)(ws + 16777216);   // 8 MB (overlay hm)
    unsigned short* h0     = (unsigned short*)(ws + 33554432);   // 4 MB
    unsigned short* h1     = (unsigned short*)(ws + 37748736);   // 4 MB
    unsigned short* w0     = (unsigned short*)(ws + 41943040);   // 2 MB
    unsigned short* w1     = (unsigned short*)(ws + 44040192);   // 2 MB
    float4*         pstats = (float4*)(ws + 46137344);           // 8 MB
    unsigned short* ph0    = (unsigned short*)(ws + 46137344);   // 4 MB (overlay pstats; dead before first logits)
    unsigned short* ph1    = (unsigned short*)(ws + 50331648);   // 4 MB (overlay pstats)
    unsigned short* wv0    = (unsigned short*)(ws + 54558720);   // 256 KB
    unsigned short* wv1    = (unsigned short*)(ws + 54820864);   // 256 KB
    unsigned short* g0     = (unsigned short*)(ws + 55083008);   // 384 KB
    unsigned short* g1     = (unsigned short*)(ws + 55476224);   // 384 KB
    float*          embgk  = (float*)(ws + 55869440);            // 12 MB (table)
    unsigned short* gk0    = (unsigned short*)(ws + 68452352);   // 96 KB
    unsigned short* gk1    = (unsigned short*)(ws + 68550656);   // 96 KB -> ends 68648960

    const bool use_tbl = (ws_size >= 68648960ULL);
    unsigned short* emb0 = h0;   // one-time reuse (free until gru t=0 writes)
    unsigned short* emb1 = h1;

    // one-time weight preps (loop-invariant)
    trans_split<<<dim3(64, 4), 256, 0, stream>>>(Wo, w0, w1, 4096, 256);
    trans_split<<<dim3(4, 8), 256, 0, stream>>>(Wv, wv0, wv1, 256, 512);
    trans_split<<<dim3(12, 4), 256, 0, stream>>>(grk, g0, g1, 768, 256);
    split_ew<<<4096, 256, 0, stream>>>(vis, vis0, vis1, 1048576);
    if (use_tbl) {
        trans_split<<<dim3(12, 1), 256, 0, stream>>>(gk, gk0, gk1, 768, 64);
        split_ew<<<256, 256, 0, stream>>>(emb, emb0, emb1, 65536);
    }

    // K1: prev_hidden = vis @ Wv + bv (epilogue also emits ph0/ph1 splits)
    mfma_gemm<512, true><<<dim3(4, 128), 256, 0, stream>>>(
        vis0, vis1, wv0, wv1, bv, ph, 256, ph0, ph1);
    // K2: hm = prev_hidden @ grk + brec (loop-invariant)
    mfma_gemm<256, false><<<dim3(12, 128), 256, 0, stream>>>(
        ph0, ph1, g0, g1, brec, hm, 768, nullptr, nullptr);
    // embgk = emb @ gk (loop-invariant table)
    if (use_tbl)
        mfma_gemm<64, false><<<dim3(12, 64), 256, 0, stream>>>(
            emb0, emb1, gk0, gk1, nullptr, embgk, 768, nullptr, nullptr);

    for (int t = 0; t < 6; ++t) {
        gru_fused<<<1024, 256, 0, stream>>>(pstats, emb,
                                            use_tbl ? embgk : nullptr,
                                            gk, bin, hm, ph, h0, h1,
                                            (t == 5) ? out_ht : nullptr,
                                            out_seq, out_sel, out_ent, t);
        logits_mfma<<<dim3(32, 64), 256, 0, stream>>>(h0, h1, w0, w1, bo, pstats);
    }
    finalize_kernel<<<128, 64, 0, stream>>>(pstats, out_seq, out_sel,
                                            out_ent, out_ml);
}

// Round 16
// 519.591 us; speedup vs baseline: 1.2219x; 1.2219x over previous
//
#include <hip/hip_runtime.h>
#include <hip/hip_fp16.h>
#include <math.h>

// ---------------------------------------------------------------------------
// Sender model, MI355X, round 16 = R14 restored (best-known, 520.5 us).
// All GEMMs on fp16x2 (Markidis) MFMA: 3 products, fp32 accumulate.
// embgk table: xm = emb[sym] @ gk == (emb @ gk)[sym] (loop-invariant gather).
// logits: R8 form -- 128x128 tile, slot-swizzled LDS, single 32 KB buffer,
// vmcnt(0)+__syncthreads per K-step, launch_bounds(256,3). 67 us/dispatch.
// Structural-variant history (all regressed vs this form): reg-dbuf 137us,
// counted-vmcnt 73us, frag-major 84us, B-stationary 93us, A-in-regs 91us.
// Law: MFMA operands must flow via global_load_lds+LDS on this compiler;
// register-residency plans beyond the accumulator get rematerialized.
// ---------------------------------------------------------------------------

typedef __attribute__((ext_vector_type(8))) _Float16 half8v;  // 16 B
typedef __attribute__((ext_vector_type(4))) float f32x4;

// slot swizzle; row stride 64 B
__device__ __forceinline__ int lds_off(int row, int slot) {
    return (row << 6) + ((slot ^ (row & 3) ^ ((row >> 2) & 3)) << 4);
}

__device__ __forceinline__ void gld_lds16(const void* src, void* dst) {
    __builtin_amdgcn_global_load_lds(
        (const __attribute__((address_space(1))) void*)src,
        (__attribute__((address_space(3))) void*)dst, 16, 0, 0);
}

template<int C>
__device__ __forceinline__ float dppf(float x) {
    return __builtin_bit_cast(float, __builtin_amdgcn_update_dpp(
        __builtin_bit_cast(int, x), __builtin_bit_cast(int, x), C, 0xF, 0xF, false));
}
template<int C>
__device__ __forceinline__ int dppi(int x) {
    return __builtin_amdgcn_update_dpp(x, x, C, 0xF, 0xF, false);
}

__device__ __forceinline__ void f16split(float v, unsigned short& u0,
                                         unsigned short& u1) {
    __half a = __float2half(v);            // RTNE
    float f = __half2float(a);
    __half b = __float2half(v - f);
    u0 = __half_as_ushort(a);
    u1 = __half_as_ushort(b);
}

__device__ __forceinline__ float fast_tanh(float x) {
    float t = __expf(-2.0f * fabsf(x));    // t in (0,1], no overflow
    float th = (1.0f - t) / (1.0f + t);
    return copysignf(th, x);
}

// ---------------- elementwise fp16x2 split (vis, emb) -----------------------
__global__ __launch_bounds__(256) void split_ew(
    const float* __restrict__ in, unsigned short* __restrict__ o0,
    unsigned short* __restrict__ o1, int n4)
{
    int i = blockIdx.x * 256 + threadIdx.x;
    if (i >= n4) return;
    float4 v = *(const float4*)&in[(size_t)i * 4];
    unsigned short a[4], b[4];
    f16split(v.x, a[0], b[0]); f16split(v.y, a[1], b[1]);
    f16split(v.z, a[2], b[2]); f16split(v.w, a[3], b[3]);
    *(uint2*)&o0[(size_t)i * 4] = *(uint2*)a;
    *(uint2*)&o1[(size_t)i * 4] = *(uint2*)b;
}

// ---------------- W[K][N] -> [n][k] fp16x2 splits (Wo, Wv, grk, gk) ---------
__global__ __launch_bounds__(256) void trans_split(
    const float* __restrict__ W, unsigned short* __restrict__ o0,
    unsigned short* __restrict__ o1, int N, int K)
{
    __shared__ float Ts[64][65];
    const int tid = threadIdx.x;
    const int n0 = blockIdx.x * 64, k0 = blockIdx.y * 64;
    const int ty = tid >> 2, tx = tid & 3;
    #pragma unroll
    for (int q = 0; q < 4; ++q) {
        float4 v = *(const float4*)&W[(size_t)(k0 + ty) * N + n0 + tx * 16 + q * 4];
        Ts[ty][tx * 16 + q * 4 + 0] = v.x; Ts[ty][tx * 16 + q * 4 + 1] = v.y;
        Ts[ty][tx * 16 + q * 4 + 2] = v.z; Ts[ty][tx * 16 + q * 4 + 3] = v.w;
    }
    __syncthreads();
    #pragma unroll
    for (int ii = 0; ii < 2; ++ii) {
        int item = tid + (ii << 8);          // 0..511
        int n = item >> 3, g = item & 7;     // n 0..63, k-group 0..7
        unsigned short u0[8], u1[8];
        #pragma unroll
        for (int e = 0; e < 8; ++e)
            f16split(Ts[g * 8 + e][n], u0[e], u1[e]);
        size_t base = (size_t)(n0 + n) * K + k0 + g * 8;
        *(uint4*)&o0[base] = *(uint4*)u0;
        *(uint4*)&o1[base] = *(uint4*)u1;
    }
}

// ---------------- fp16x2 MFMA GEMM, 64x64 tile (K1, K2, embgk) --------------
// 4 waves (2x2), wave tile 32x32 = 2x2 frags of 16x16x32 f16, 3 products.
// Single-buffer 16 KB LDS. SPLIT: also emit fp16x2 split of C (K1 -> ph0/ph1).
// bias may be nullptr (embgk).
template<int KTOT, bool SPLIT>
__global__ __launch_bounds__(256) void mfma_gemm(
    const unsigned short* __restrict__ a0s, const unsigned short* __restrict__ a1s,
    const unsigned short* __restrict__ b0s, const unsigned short* __restrict__ b1s,
    const float* __restrict__ bias, float* __restrict__ C, int ldc,
    unsigned short* __restrict__ s0, unsigned short* __restrict__ s1)
{
    __shared__ char lds[16384];
    const int tid = threadIdx.x;
    const int w = tid >> 6, lane = tid & 63;
    const int c16 = lane & 15, rg = lane >> 4;
    const int m0 = blockIdx.y << 6, n0 = blockIdx.x << 6;
    const int arow0 = (w >> 1) << 5, brow0 = (w & 1) << 5;

    const unsigned short* segsrc = (w == 0) ? a0s : (w == 1) ? a1s
                                 : (w == 2) ? b0s : b1s;
    const int segrow0 = (w < 2) ? m0 : n0;

    f32x4 acc[2][2] = {};

    for (int t = 0; t < KTOT / 32; ++t) {
        const int k0 = t << 5;
        #pragma unroll
        for (int q = 0; q < 4; ++q) {
            int row = (q << 4) + (lane >> 2);
            int slot = (lane & 3) ^ (row & 3) ^ ((row >> 2) & 3);
            gld_lds16(segsrc + (size_t)(segrow0 + row) * KTOT + k0 + (slot << 3),
                      &lds[(w << 12) + (q << 10)]);
        }
        asm volatile("s_waitcnt vmcnt(0)" ::: "memory");
        __syncthreads();
        half8v afr[2][2], bfr[2][2];
        #pragma unroll
        for (int i = 0; i < 2; ++i) {
            int oa = lds_off(arow0 + (i << 4) + c16, rg);
            afr[i][0] = *(half8v*)&lds[oa];
            afr[i][1] = *(half8v*)&lds[4096 + oa];
            int ob = lds_off(brow0 + (i << 4) + c16, rg);
            bfr[i][0] = *(half8v*)&lds[8192 + ob];
            bfr[i][1] = *(half8v*)&lds[12288 + ob];
        }
        #pragma unroll
        for (int i = 0; i < 2; ++i)
            #pragma unroll
            for (int j = 0; j < 2; ++j) {
                f32x4 c = acc[i][j];
                c = __builtin_amdgcn_mfma_f32_16x16x32_f16(afr[i][0], bfr[j][0], c, 0, 0, 0);
                c = __builtin_amdgcn_mfma_f32_16x16x32_f16(afr[i][1], bfr[j][0], c, 0, 0, 0);
                c = __builtin_amdgcn_mfma_f32_16x16x32_f16(afr[i][0], bfr[j][1], c, 0, 0, 0);
                acc[i][j] = c;
            }
        __syncthreads();
    }

    #pragma unroll
    for (int j = 0; j < 2; ++j) {
        int col = n0 + brow0 + (j << 4) + c16;
        float bb = bias ? bias[col] : 0.0f;
        #pragma unroll
        for (int i = 0; i < 2; ++i)
            #pragma unroll
            for (int reg = 0; reg < 4; ++reg) {
                int row = m0 + arow0 + (i << 4) + (rg << 2) + reg;
                float v = acc[i][j][reg] + bb;
                C[(size_t)row * ldc + col] = v;
                if (SPLIT) {
                    unsigned short u0, u1;
                    f16split(v, u0, u1);
                    s0[(size_t)row * ldc + col] = u0;
                    s1[(size_t)row * ldc + col] = u1;
                }
            }
    }
}

// ---------------- gru_fused: merge(t-1) + embgk gather + GRU + h split ------
// 8 rows/block. t>0: merge step t-1's 64 pstats panels for these rows,
// write outputs for t-1; xm from embgk table (or fallback x@gk path).
__global__ __launch_bounds__(256) void gru_fused(
    const float4* __restrict__ pstats, const float* __restrict__ emb,
    const float* __restrict__ embgk,
    const float* __restrict__ gk, const float* __restrict__ b_in,
    const float* __restrict__ hm, const float* __restrict__ ph,
    unsigned short* __restrict__ h0, unsigned short* __restrict__ h1,
    float* __restrict__ ht_out, float* __restrict__ out_seq,
    float* __restrict__ out_sel, float* __restrict__ out_ent, int t)
{
    __shared__ float xsT[64][8];
    __shared__ int syms_lds[8];
    const int tid = threadIdx.x;
    const int row0 = blockIdx.x * 8;
    float az[8], ar[8], ah[8];
    const float bz = b_in[tid], br = b_in[256 + tid], bh = b_in[512 + tid];
    #pragma unroll
    for (int r = 0; r < 8; ++r) { az[r] = bz; ar[r] = br; ah[r] = bh; }

    if (t > 0) {
        const int r = tid >> 5, p = tid & 31;
        const int row = row0 + r;
        float4 pa = pstats[(size_t)p * 8192 + row];
        float4 pb = pstats[(size_t)(p + 32) * 8192 + row];
        float M = pa.x, S = pa.y + pb.y, Q = pa.z + pb.z;
        int A = __float_as_int(pa.w);
        { int a2 = __float_as_int(pb.w);
          if (pb.x > M || (pb.x == M && a2 < A)) { M = pb.x; A = a2; } }
        #pragma unroll
        for (int off = 1; off < 32; off <<= 1) {
            float m2 = __shfl_xor(M, off);
            float s2 = __shfl_xor(S, off);
            float q2 = __shfl_xor(Q, off);
            int   a2 = __shfl_xor(A, off);
            S += s2; Q += q2;
            if (m2 > M || (m2 == M && a2 < A)) { M = m2; A = a2; }
        }
        if (p == 0) {
            float lse = __logf(S);
            float sel = M - lse;
            float ent = lse - Q / S;
            out_seq[(size_t)row * 6 + (t - 1)] = (float)A;
            out_sel[(size_t)row * 6 + (t - 1)] = sel;
            float ea = (t == 1) ? ent : (out_ent[row] + ent);
            out_ent[row] = ea;
            syms_lds[r] = A;
        }
        __syncthreads();
        if (embgk) {
            // xm = (emb @ gk)[sym] -- 24 coalesced loads, no GEMM
            #pragma unroll
            for (int r2 = 0; r2 < 8; ++r2) {
                size_t b = (size_t)syms_lds[r2] * 768 + tid;
                az[r2] += embgk[b];
                ar[r2] += embgk[b + 256];
                ah[r2] += embgk[b + 512];
            }
        } else {
            // fallback: gather emb + x @ gk in VALU (R13 path)
            for (int l = tid; l < 512; l += 256) {
                int r2 = l >> 6, e = l & 63;
                xsT[e][r2] = emb[(size_t)syms_lds[r2] * 64 + e];
            }
            __syncthreads();
            #pragma unroll 4
            for (int e = 0; e < 64; ++e) {
                float kz  = gk[e * 768 + tid];
                float kr_ = gk[e * 768 + 256 + tid];
                float kh  = gk[e * 768 + 512 + tid];
                float4 x0 = *(float4*)&xsT[e][0];
                float4 x1 = *(float4*)&xsT[e][4];
                float xv[8] = {x0.x, x0.y, x0.z, x0.w, x1.x, x1.y, x1.z, x1.w};
                #pragma unroll
                for (int r2 = 0; r2 < 8; ++r2) {
                    az[r2] = fmaf(xv[r2], kz, az[r2]);
                    ar[r2] = fmaf(xv[r2], kr_, ar[r2]);
                    ah[r2] = fmaf(xv[r2], kh, ah[r2]);
                }
            }
        }
    }
    #pragma unroll
    for (int r = 0; r < 8; ++r) {
        const int row = row0 + r;
        float hz  = hm[(size_t)row * 768 + tid];
        float hr  = hm[(size_t)row * 768 + 256 + tid];
        float hh  = hm[(size_t)row * 768 + 512 + tid];
        float phv = ph[(size_t)row * 256 + tid];
        float z  = 1.0f / (1.0f + __expf(-(az[r] + hz)));
        float rr = 1.0f / (1.0f + __expf(-(ar[r] + hr)));
        float ht = fast_tanh(ah[r] + rr * hh);
        float hv = z * phv + (1.0f - z) * ht;
        size_t idx = (size_t)row * 256 + tid;
        unsigned short u0, u1;
        f16split(hv, u0, u1);
        h0[idx] = u0; h1[idx] = u1;
        if (ht_out) ht_out[idx] = hv;
    }
}

// ---------------- logits: 128x128 fp16x2 MFMA, single-buf 32 KB (R8) --------
__global__ __launch_bounds__(256, 3) void logits_mfma(
    const unsigned short* __restrict__ h0, const unsigned short* __restrict__ h1,
    const unsigned short* __restrict__ w0, const unsigned short* __restrict__ w1,
    const float* __restrict__ bo, float4* __restrict__ pstats)
{
    __shared__ char lds[32768];
    const int tid = threadIdx.x;
    const int w = tid >> 6, lane = tid & 63;
    const int c16 = lane & 15, rg = lane >> 4;
    const int m0 = blockIdx.y << 7, n0 = blockIdx.x << 7;
    const int arow0 = (w >> 1) << 6, brow0 = (w & 1) << 6;

    const unsigned short* segsrc = (w == 0) ? h0 : (w == 1) ? h1
                                 : (w == 2) ? w0 : w1;
    const int segrow0 = (w < 2) ? m0 : n0;

    f32x4 acc[4][4] = {};

    for (int t = 0; t < 8; ++t) {
        const int k0 = t << 5;
        #pragma unroll
        for (int q = 0; q < 8; ++q) {          // stage this K-step (own segment)
            int row = (q << 4) + (lane >> 2);
            int slot = (lane & 3) ^ (row & 3) ^ ((row >> 2) & 3);
            gld_lds16(segsrc + (size_t)(segrow0 + row) * 256 + k0 + (slot << 3),
                      &lds[(w << 13) + (q << 10)]);
        }
        asm volatile("s_waitcnt vmcnt(0)" ::: "memory");
        __syncthreads();
        half8v afr[4][2];
        #pragma unroll
        for (int i = 0; i < 4; ++i) {
            int o = lds_off(arow0 + (i << 4) + c16, rg);
            afr[i][0] = *(half8v*)&lds[o];
            afr[i][1] = *(half8v*)&lds[8192 + o];
        }
        #pragma unroll
        for (int j = 0; j < 4; ++j) {
            int o = lds_off(brow0 + (j << 4) + c16, rg);
            half8v b0 = *(half8v*)&lds[16384 + o];
            half8v b1 = *(half8v*)&lds[24576 + o];
            #pragma unroll
            for (int i = 0; i < 4; ++i) {
                f32x4 c = acc[i][j];
                c = __builtin_amdgcn_mfma_f32_16x16x32_f16(afr[i][0], b0, c, 0, 0, 0);
                c = __builtin_amdgcn_mfma_f32_16x16x32_f16(afr[i][1], b0, c, 0, 0, 0);
                c = __builtin_amdgcn_mfma_f32_16x16x32_f16(afr[i][0], b1, c, 0, 0, 0);
                acc[i][j] = c;
            }
        }
        __syncthreads();
    }

    // epilogue: raw softmax stats + DPP reductions across the 16 c16 lanes.
    const int wn0 = n0 + brow0;
    float bov[4];
    #pragma unroll
    for (int j = 0; j < 4; ++j) bov[j] = bo[wn0 + j * 16 + c16];
    #pragma unroll
    for (int i = 0; i < 4; ++i) {
        #pragma unroll
        for (int reg = 0; reg < 4; ++reg) {
            float l0 = acc[i][0][reg] + bov[0];
            float l1 = acc[i][1][reg] + bov[1];
            float l2 = acc[i][2][reg] + bov[2];
            float l3 = acc[i][3][reg] + bov[3];
            float m = l0; int a = wn0 + c16;
            if (l1 > m) { m = l1; a = wn0 + 16 + c16; }
            if (l2 > m) { m = l2; a = wn0 + 32 + c16; }
            if (l3 > m) { m = l3; a = wn0 + 48 + c16; }
            float e0 = __expf(l0), e1 = __expf(l1), e2 = __expf(l2), e3 = __expf(l3);
            float s = (e0 + e1) + (e2 + e3);
            float q = fmaf(l0, e0, fmaf(l1, e1, fmaf(l2, e2, l3 * e3)));
            s += dppf<0x108>(s); s += dppf<0x104>(s);
            s += dppf<0x102>(s); s += dppf<0x101>(s);
            q += dppf<0x108>(q); q += dppf<0x104>(q);
            q += dppf<0x102>(q); q += dppf<0x101>(q);
            #define MMERGE(C) { float m2 = dppf<C>(m); int a2 = dppi<C>(a); \
                bool bt = (m2 > m) || (m2 == m && a2 < a); \
                m = bt ? m2 : m; a = bt ? a2 : a; }
            MMERGE(0x108) MMERGE(0x104) MMERGE(0x102) MMERGE(0x101)
            #undef MMERGE
            if (c16 == 0) {
                int grow = m0 + arow0 + (i << 4) + (rg << 2) + reg;
                pstats[(size_t)((blockIdx.x << 1) + (w & 1)) * 8192 + grow] =
                    make_float4(m, s, q, __int_as_float(a));
            }
        }
    }
}

// ---------------- final finalize: merge t=5 panels, close outputs -----------
__global__ __launch_bounds__(64) void finalize_kernel(
    const float4* __restrict__ pstats, float* __restrict__ out_seq,
    float* __restrict__ out_sel, float* __restrict__ out_ent,
    float* __restrict__ out_ml)
{
    const int row = blockIdx.x * 64 + threadIdx.x;
    float M = -INFINITY, S = 0.f, Q = 0.f; int A = 0;
    #pragma unroll 8
    for (int p = 0; p < 64; ++p) {
        float4 pp = pstats[(size_t)p * 8192 + row];
        S += pp.y; Q += pp.z;
        int a2 = __float_as_int(pp.w);
        if (pp.x > M || (pp.x == M && a2 < A)) { M = pp.x; A = a2; }
    }
    float lse = __logf(S);
    float sel = M - lse;
    float ent = lse - Q / S;
    out_seq[(size_t)row * 6 + 5] = (float)A;
    out_sel[(size_t)row * 6 + 5] = sel;
    out_ent[row] = (out_ent[row] + ent) * (1.0f / 6.0f);
    out_ml[row] = 6.0f;
}

// ---------------------------------------------------------------------------
extern "C" void kernel_launch(void* const* d_in, const int* in_sizes, int n_in,
                              void* d_out, int out_size, void* d_ws, size_t ws_size,
                              hipStream_t stream) {
    const float* vis  = (const float*)d_in[0];
    const float* Wv   = (const float*)d_in[1];
    const float* bv   = (const float*)d_in[2];
    const float* gk   = (const float*)d_in[3];
    const float* grk  = (const float*)d_in[4];
    const float* bin  = (const float*)d_in[5];
    const float* brec = (const float*)d_in[6];
    const float* Wo   = (const float*)d_in[7];
    const float* bo   = (const float*)d_in[8];
    const float* emb  = (const float*)d_in[9];

    float* out = (float*)d_out;
    float* out_seq = out;                 // (8192, 6)
    float* out_sel = out + 49152;         // (8192, 6)
    float* out_ent = out + 98304;         // (8192,)
    float* out_ml  = out + 106496;        // (8192,)
    float* out_ht  = out + 114688;        // (8192, 256)

    char* ws = (char*)d_ws;
    float*          ph     = (float*)(ws);                       // 8 MB
    float*          hm     = (float*)(ws + 8388608);             // 24 MB
    unsigned short* vis0   = (unsigned short*)(ws + 8388608);    // 8 MB (overlay hm; dead before K2)
    unsigned short* vis1   = (unsigned short*)(ws + 16777216);   // 8 MB (overlay hm)
    unsigned short* h0     = (unsigned short*)(ws + 33554432);   // 4 MB
    unsigned short* h1     = (unsigned short*)(ws + 37748736);   // 4 MB
    unsigned short* w0     = (unsigned short*)(ws + 41943040);   // 2 MB
    unsigned short* w1     = (unsigned short*)(ws + 44040192);   // 2 MB
    float4*         pstats = (float4*)(ws + 46137344);           // 8 MB
    unsigned short* ph0    = (unsigned short*)(ws + 46137344);   // 4 MB (overlay pstats; dead before first logits)
    unsigned short* ph1    = (unsigned short*)(ws + 50331648);   // 4 MB (overlay pstats)
    unsigned short* wv0    = (unsigned short*)(ws + 54558720);   // 256 KB
    unsigned short* wv1    = (unsigned short*)(ws + 54820864);   // 256 KB
    unsigned short* g0     = (unsigned short*)(ws + 55083008);   // 384 KB
    unsigned short* g1     = (unsigned short*)(ws + 55476224);   // 384 KB
    float*          embgk  = (float*)(ws + 55869440);            // 12 MB (table)
    unsigned short* gk0    = (unsigned short*)(ws + 68452352);   // 96 KB
    unsigned short* gk1    = (unsigned short*)(ws + 68550656);   // 96 KB -> ends 68648960

    const bool use_tbl = (ws_size >= 68648960ULL);
    // emb splits (one-time) reuse h0/h1 (free until gru step 0 writes them)
    unsigned short* emb0 = h0;
    unsigned short* emb1 = h1;

    // one-time weight preps (loop-invariant)
    trans_split<<<dim3(64, 4), 256, 0, stream>>>(Wo, w0, w1, 4096, 256);
    trans_split<<<dim3(4, 8), 256, 0, stream>>>(Wv, wv0, wv1, 256, 512);
    trans_split<<<dim3(12, 4), 256, 0, stream>>>(grk, g0, g1, 768, 256);
    split_ew<<<4096, 256, 0, stream>>>(vis, vis0, vis1, 1048576);
    if (use_tbl) {
        trans_split<<<dim3(12, 1), 256, 0, stream>>>(gk, gk0, gk1, 768, 64);
        split_ew<<<256, 256, 0, stream>>>(emb, emb0, emb1, 65536);
    }

    // K1: prev_hidden = vis @ Wv + bv (epilogue also emits ph0/ph1 splits)
    mfma_gemm<512, true><<<dim3(4, 128), 256, 0, stream>>>(
        vis0, vis1, wv0, wv1, bv, ph, 256, ph0, ph1);
    // K2: hm = prev_hidden @ grk + brec (loop-invariant)
    mfma_gemm<256, false><<<dim3(12, 128), 256, 0, stream>>>(
        ph0, ph1, g0, g1, brec, hm, 768, nullptr, nullptr);
    // embgk = emb @ gk (loop-invariant table)
    if (use_tbl)
        mfma_gemm<64, false><<<dim3(12, 64), 256, 0, stream>>>(
            emb0, emb1, gk0, gk1, nullptr, embgk, 768, nullptr, nullptr);

    for (int t = 0; t < 6; ++t) {
        gru_fused<<<1024, 256, 0, stream>>>(pstats, emb,
                                            use_tbl ? embgk : nullptr,
                                            gk, bin, hm, ph, h0, h1,
                                            (t == 5) ? out_ht : nullptr,
                                            out_seq, out_sel, out_ent, t);
        logits_mfma<<<dim3(32, 64), 256, 0, stream>>>(h0, h1, w0, w1, bo, pstats);
    }
    finalize_kernel<<<128, 64, 0, stream>>>(pstats, out_seq, out_sel,
                                            out_ent, out_ml);
}